// Round 3
// baseline (237.767 us; speedup 1.0000x reference)
//
#include <hip/hip_runtime.h>

#define EPS 1e-6f

typedef short s8v __attribute__((ext_vector_type(8)));
typedef float f4v __attribute__((ext_vector_type(4)));

typedef const __attribute__((address_space(1))) unsigned GSrc;
typedef __attribute__((address_space(3))) unsigned LDst;

// split (a,b) -> packed bf16 hi + packed bf16 lo, RTNE both (hw cvt_pk).
// hi+lo reconstruction is exact to 2^-17 |x| — same numerics as the old
// hand-rolled RTNE split2, ~3x fewer VALU ops.
__device__ __forceinline__ void cvtpk2(float a, float b, unsigned& h, unsigned& l) {
    unsigned hh, ll;
    asm("v_cvt_pk_bf16_f32 %0, %1, %2" : "=v"(hh) : "v"(a), "v"(b));
    float ra = a - __uint_as_float(hh << 16);
    float rb = b - __uint_as_float(hh & 0xffff0000u);
    asm("v_cvt_pk_bf16_f32 %0, %1, %2" : "=v"(ll) : "v"(ra), "v"(rb));
    h = hh;
    l = ll;
}

__device__ __forceinline__ s8v ld16(const unsigned short* p) {
    return *(const s8v*)p;   // ds_read_b128 / global_load_dwordx4
}

__device__ __forceinline__ double shfl_xor_dbl(double x, int msk) {
    long long v = __double_as_longlong(x);
    int lo = (int)(v & 0xffffffffll), hi = (int)(v >> 32);
    lo = __shfl_xor(lo, msk, 64);
    hi = __shfl_xor(hi, msk, 64);
    return __longlong_as_double(((long long)hi << 32) | (unsigned)lo);
}

union U8 { unsigned u[4]; s8v v; };

// Raw-tile LDS layout for phase1: a 32-row stage is 8 chunks of 4 rows.
// Each chunk is the linear 1 KB block one global_load_lds writes, chunks
// placed at stride 1040 B (260 floats). Transpose fragment reads then hit
// bank (m + 8q) mod 32 -> uniform 2 lanes/bank = conflict-free (m136).
#define CHW 260   // floats per chunk
__device__ __forceinline__ int fidx(int s, int d) {   // s: stage-local row 0..31
    return (s >> 2) * CHW + (s & 3) * 64 + d;
}

// ---------------- Phase 1: partial M (split-bf16 MFMA) + partial z (fp64) ----------------
// grid (8 chunks, 64 heads), 512 threads (8 waves). chunk = 512 s-rows.
// 16 stages of 32 rows; raw fp32 staged by global_load_lds (async DMA, no dest
// VGPRs -> compiler cannot sink the prefetch). 3 buffers, loads 2 stages ahead,
// counted s_waitcnt vmcnt(2) (never 0 in-loop) + ONE barrier per stage.
// Split to bf16 hi/lo happens at the LDS->reg boundary via v_cvt_pk_bf16_f32.
__global__ __launch_bounds__(512, 4) void mm_phase1(const float* __restrict__ Kg,
                                                    const float* __restrict__ Vg,
                                                    float* __restrict__ partM,
                                                    double* __restrict__ partZ) {
    __shared__ __align__(16) float Kraw[3][8 * CHW];   // 3 x 8320 B
    __shared__ __align__(16) float Vraw[3][8 * CHW];   // total LDS 49.9 KB

    const int chunk = blockIdx.x;
    const int head  = blockIdx.y;
    const int t = threadIdx.x;
    const int lane = t & 63;
    const int w = t >> 6;
    const int m = lane & 15, q = lane >> 4;
    const int rt_ = w >> 1, ch = w & 1;   // wave's M row-tile / col-half

    const long hbase = (long)head * 4096 * 64;
    const int srow0 = chunk * 512;

    f4v acc[2];
    acc[0] = (f4v){0.f, 0.f, 0.f, 0.f};
    acc[1] = (f4v){0.f, 0.f, 0.f, 0.f};
    double z1 = 0.0;   // fp64 z partial for column d = rt_*16+m (ch==0 waves)

    // wave w DMAs chunk w (4 rows) of K and V: lane l sources row w*4+(l>>4),
    // cols (l&15)*4..+4 -> lands at LDS float offset w*260 + 4l (matches fidx).
    auto stage_dma = [&](int st, int bi) {
        const long rb = hbase + (long)(srow0 + st * 32 + w * 4 + (lane >> 4)) * 64 + (lane & 15) * 4;
        __builtin_amdgcn_global_load_lds((GSrc*)(Kg + rb), (LDst*)&Kraw[bi][w * CHW], 16, 0, 0);
        __builtin_amdgcn_global_load_lds((GSrc*)(Vg + rb), (LDst*)&Vraw[bi][w * CHW], 16, 0, 0);
    };

    stage_dma(0, 0);
    stage_dma(1, 1);

#pragma unroll
    for (int st = 0; st < 16; ++st) {
        // wait THIS stage's 2 DMAs (issued 2 stages ago); st+1's stay in flight
        if (st < 15) asm volatile("s_waitcnt vmcnt(2)" ::: "memory");
        else         asm volatile("s_waitcnt vmcnt(0)" ::: "memory");
        __builtin_amdgcn_s_barrier();   // all waves' stage-st chunks now in LDS;
                                        // also: everyone done reading buf[(st+2)%3]
        if (st < 14) stage_dma(st + 2, (st + 2) % 3);

        const float* Kb = Kraw[st % 3];
        const float* Vb = Vraw[st % 3];

        // ---- fragment gather (transpose reads, conflict-free) ----
        const int dA = rt_ * 16 + m;
        float af[8], bf0[8], bf1[8];
#pragma unroll
        for (int j = 0; j < 8; ++j) af[j]  = Kb[fidx(q * 8 + j, dA)];
#pragma unroll
        for (int j = 0; j < 8; ++j) bf0[j] = Vb[fidx(q * 8 + j, (ch * 2 + 0) * 16 + m)];
#pragma unroll
        for (int j = 0; j < 8; ++j) bf1[j] = Vb[fidx(q * 8 + j, (ch * 2 + 1) * 16 + m)];

        if (ch == 0) {   // z: each K element summed exactly once (ch==0 waves cover all d)
#pragma unroll
            for (int j = 0; j < 8; ++j) z1 += (double)af[j];
        }

        // ---- split to bf16 hi/lo in-register ----
        U8 ah, al, b0h, b0l, b1h, b1l;
#pragma unroll
        for (int p = 0; p < 4; ++p) {
            cvtpk2(af[2 * p],  af[2 * p + 1],  ah.u[p],  al.u[p]);
            cvtpk2(bf0[2 * p], bf0[2 * p + 1], b0h.u[p], b0l.u[p]);
            cvtpk2(bf1[2 * p], bf1[2 * p + 1], b1h.u[p], b1l.u[p]);
        }

        // ---- MFMA: wave owns M rows [rt_*16,+16), cols [ch*32,+32) ----
        __builtin_amdgcn_s_setprio(1);
        acc[0] = __builtin_amdgcn_mfma_f32_16x16x32_bf16(ah.v, b0h.v, acc[0], 0, 0, 0);
        acc[0] = __builtin_amdgcn_mfma_f32_16x16x32_bf16(ah.v, b0l.v, acc[0], 0, 0, 0);
        acc[0] = __builtin_amdgcn_mfma_f32_16x16x32_bf16(al.v, b0h.v, acc[0], 0, 0, 0);
        acc[1] = __builtin_amdgcn_mfma_f32_16x16x32_bf16(ah.v, b1h.v, acc[1], 0, 0, 0);
        acc[1] = __builtin_amdgcn_mfma_f32_16x16x32_bf16(ah.v, b1l.v, acc[1], 0, 0, 0);
        acc[1] = __builtin_amdgcn_mfma_f32_16x16x32_bf16(al.v, b1h.v, acc[1], 0, 0, 0);
        __builtin_amdgcn_s_setprio(0);
    }

    // write partial M (C layout: col=lane&15, row=(lane>>4)*4+reg)
    float* pm = partM + ((long)(head * 8 + chunk) << 12);
#pragma unroll
    for (int c = 0; c < 2; ++c)
#pragma unroll
        for (int r2 = 0; r2 < 4; ++r2)
            pm[(rt_ * 16 + q * 4 + r2) * 64 + (ch * 2 + c) * 16 + m] = acc[c][r2];

    // z: reduce over the 4 q-lanes sharing m; ch==0 waves hold all 64 columns
    z1 += shfl_xor_dbl(z1, 16);
    z1 += shfl_xor_dbl(z1, 32);
    if (ch == 0 && lane < 16)
        partZ[(head * 8 + chunk) * 64 + rt_ * 16 + lane] = z1;
}

// ---------------- Reduce: sum chunks -> Mt split-bf16 planes + z fp64 ----------------
// grid (4 k-slices, 64 heads). Emits the transposed hi/lo bf16 planes ONCE so
// phase2 needs no LDS staging / re-split.
__global__ __launch_bounds__(256) void mm_reduce(const float* __restrict__ partM,
                                                 const double* __restrict__ partZ,
                                                 unsigned short* __restrict__ Mthg,
                                                 unsigned short* __restrict__ Mtlg,
                                                 double* __restrict__ zf) {
    __shared__ float Ml[16][68];
    const int b = blockIdx.x, h = blockIdx.y, t = threadIdx.x;
#pragma unroll
    for (int it = 0; it < 4; ++it) {
        const int fl = it * 256 + t;          // 0..1023 within slice
        const int f = b * 1024 + fl;          // flat = k*64 + n
        float s = 0.f;
#pragma unroll
        for (int c = 0; c < 8; ++c) s += partM[(long)(h * 8 + c) * 4096 + f];
        Ml[fl >> 6][fl & 63] = s;
    }
    if (b == 0 && t < 64) {
        double s = 0.0;
#pragma unroll
        for (int c = 0; c < 8; ++c) s += partZ[(h * 8 + c) * 64 + t];
        zf[h * 64 + t] = s;
    }
    __syncthreads();
    // Mt[n][k] = M[k][n], split to bf16 hi/lo: thread t -> row n=t>>2, k = b*16+(t&3)*4..+4
    const int n = t >> 2, kq = (t & 3) * 4;
    uint2 uh, ul;
    cvtpk2(Ml[kq + 0][n], Ml[kq + 1][n], uh.x, ul.x);
    cvtpk2(Ml[kq + 2][n], Ml[kq + 3][n], uh.y, ul.y);
    const long o = (long)h * 4096 + n * 64 + b * 16 + kq;
    *(uint2*)(Mthg + o) = uh;
    *(uint2*)(Mtlg + o) = ul;
}

// ---------------- Phase 2: out = (Q @ M) / (fp32 den) ----------------
// grid (32 s-blocks, 64 heads), 256 threads, 128 rows/block.
// B fragments straight from global (Mt planes are 1 MB -> L2/L3-hot),
// double-buffered across the ct loop. den from qa registers (fp64 butterfly).
// Only LDS: zl[64]; one raw lgkm-barrier (Q/frag loads survive it).
__global__ __launch_bounds__(256, 4) void mm_phase2(const float* __restrict__ Qg,
                                                    const unsigned short* __restrict__ Mthg,
                                                    const unsigned short* __restrict__ Mtlg,
                                                    const double* __restrict__ zf,
                                                    float* __restrict__ outg) {
    __shared__ __align__(16) float zl[64];

    const int sb = blockIdx.x, h = blockIdx.y;
    const int t = threadIdx.x, lane = t & 63, w = t >> 6;
    const long hq = (long)h * 4096 * 64;
    const int s0 = sb * 128;
    const int m = lane & 15, q = lane >> 4;

    // ---- A-fragment loads first: pull the Q tile from HBM early ----
    float4 qa[8];
    {
        const float* qr0 = Qg + hq + (long)(s0 + w * 32 + m) * 64;
        const float* qr1 = qr0 + 16 * 64;
#pragma unroll
        for (int i = 0; i < 2; ++i) {
            qa[0 + i] = *(const float4*)(qr0 + q * 8 + 4 * i);
            qa[2 + i] = *(const float4*)(qr0 + 32 + q * 8 + 4 * i);
            qa[4 + i] = *(const float4*)(qr1 + q * 8 + 4 * i);
            qa[6 + i] = *(const float4*)(qr1 + 32 + q * 8 + 4 * i);
        }
    }

    // ---- B-fragment bases + ct=0 prefetch (L2-hot global, 16B/lane) ----
    const unsigned short* mh = Mthg + (long)h * 4096;
    const unsigned short* ml = Mtlg + (long)h * 4096;
    s8v fh0[2], fl0[2], fh1[2], fl1[2];
    auto ldfrag = [&](int ct, int bsel) {
        const unsigned short* r = mh + (ct * 16 + m) * 64 + q * 8;
        const unsigned short* s = ml + (ct * 16 + m) * 64 + q * 8;
        fh0[bsel] = ld16(r);
        fl0[bsel] = ld16(s);
        fh1[bsel] = ld16(r + 32);
        fl1[bsel] = ld16(s + 32);
    };
    ldfrag(0, 0);

    if (t < 64) zl[t] = (float)zf[h * 64 + t];
    asm volatile("s_waitcnt lgkmcnt(0)\n\ts_barrier" ::: "memory");   // zl visible

    // ---- den from registers: fp32-rounded products (no FMA), exact fp64 sum,
    // then fp32 + EPS. The 4 lanes sharing m jointly hold a full Q row.
    float dv[2][4];
    {
        float zq[16];
        *(float4*)&zq[0]  = *(const float4*)&zl[q * 8];
        *(float4*)&zq[4]  = *(const float4*)&zl[q * 8 + 4];
        *(float4*)&zq[8]  = *(const float4*)&zl[32 + q * 8];
        *(float4*)&zq[12] = *(const float4*)&zl[32 + q * 8 + 4];
        const float* qp0 = (const float*)&qa[0];
        const float* qp1 = (const float*)&qa[4];
        double dp0 = 0.0, dp1 = 0.0;
#pragma unroll
        for (int j = 0; j < 16; ++j) {
            dp0 += (double)__fmul_rn(qp0[j], zq[j]);
            dp1 += (double)__fmul_rn(qp1[j], zq[j]);
        }
        dp0 += shfl_xor_dbl(dp0, 16); dp0 += shfl_xor_dbl(dp0, 32);
        dp1 += shfl_xor_dbl(dp1, 16); dp1 += shfl_xor_dbl(dp1, 32);
        const float den0 = __fadd_rn((float)dp0, EPS);   // row w*32 + m
        const float den1 = __fadd_rn((float)dp1, EPS);   // row w*32 + 16 + m
        // redistribute: output rows are q*4+r2 (+16*rt); lane q*4+r2 holds them
#pragma unroll
        for (int r2 = 0; r2 < 4; ++r2) {
            dv[0][r2] = __shfl(den0, q * 4 + r2, 64);
            dv[1][r2] = __shfl(den1, q * 4 + r2, 64);
        }
    }

    // ---- A fragments (split bf16 hi/lo via cvt_pk), both row-tiles ----
    U8 ah[2][2], al[2][2];
#pragma unroll
    for (int rt = 0; rt < 2; ++rt) {
        const float4* qq = &qa[rt * 4];
        cvtpk2(qq[0].x, qq[0].y, ah[rt][0].u[0], al[rt][0].u[0]);
        cvtpk2(qq[0].z, qq[0].w, ah[rt][0].u[1], al[rt][0].u[1]);
        cvtpk2(qq[1].x, qq[1].y, ah[rt][0].u[2], al[rt][0].u[2]);
        cvtpk2(qq[1].z, qq[1].w, ah[rt][0].u[3], al[rt][0].u[3]);
        cvtpk2(qq[2].x, qq[2].y, ah[rt][1].u[0], al[rt][1].u[0]);
        cvtpk2(qq[2].z, qq[2].w, ah[rt][1].u[1], al[rt][1].u[1]);
        cvtpk2(qq[3].x, qq[3].y, ah[rt][1].u[2], al[rt][1].u[2]);
        cvtpk2(qq[3].z, qq[3].w, ah[rt][1].u[3], al[rt][1].u[3]);
    }

    // ---- ct loop, B fragments double-buffered from global ----
#pragma unroll
    for (int ct = 0; ct < 4; ++ct) {
        if (ct < 3) ldfrag(ct + 1, (ct + 1) & 1);
        const int cb = ct & 1;
#pragma unroll
        for (int rt = 0; rt < 2; ++rt) {
            f4v acc = (f4v){0.f, 0.f, 0.f, 0.f};
            acc = __builtin_amdgcn_mfma_f32_16x16x32_bf16(ah[rt][0].v, fh0[cb], acc, 0, 0, 0);
            acc = __builtin_amdgcn_mfma_f32_16x16x32_bf16(ah[rt][0].v, fl0[cb], acc, 0, 0, 0);
            acc = __builtin_amdgcn_mfma_f32_16x16x32_bf16(al[rt][0].v, fh0[cb], acc, 0, 0, 0);
            acc = __builtin_amdgcn_mfma_f32_16x16x32_bf16(ah[rt][1].v, fh1[cb], acc, 0, 0, 0);
            acc = __builtin_amdgcn_mfma_f32_16x16x32_bf16(ah[rt][1].v, fl1[cb], acc, 0, 0, 0);
            acc = __builtin_amdgcn_mfma_f32_16x16x32_bf16(al[rt][1].v, fh1[cb], acc, 0, 0, 0);
            const long rb = hq + (long)(s0 + w * 32 + rt * 16 + q * 4) * 64 + ct * 16 + m;
#pragma unroll
            for (int r2 = 0; r2 < 4; ++r2)
                outg[rb + (long)r2 * 64] = __fdiv_rn(acc[r2], dv[rt][r2]);   // IEEE fp32 divide
        }
    }
}

extern "C" void kernel_launch(void* const* d_in, const int* in_sizes, int n_in,
                              void* d_out, int out_size, void* d_ws, size_t ws_size,
                              hipStream_t stream) {
    const float* K = (const float*)d_in[0];
    const float* V = (const float*)d_in[1];
    const float* Q = (const float*)d_in[2];
    float* out = (float*)d_out;

    char* ws = (char*)d_ws;
    float*          partM = (float*)ws;                       // 64*8*4096*4 = 8 MiB
    double*         partZ = (double*)(ws + 8388608);          // 64*8*64*8   = 256 KiB
    unsigned short* Mthg  = (unsigned short*)(ws + 8650752);  // 64*4096*2   = 512 KiB
    unsigned short* Mtlg  = (unsigned short*)(ws + 9175040);  // 64*4096*2   = 512 KiB
    double*         zfin  = (double*)(ws + 9699328);          // 64*64*8     = 32 KiB

    mm_phase1<<<dim3(8, 64), 512, 0, stream>>>(K, V, partM, partZ);
    mm_reduce<<<dim3(4, 64), 256, 0, stream>>>(partM, partZ, Mthg, Mtlg, zfin);
    mm_phase2<<<dim3(32, 64), 256, 0, stream>>>(Q, Mthg, Mtlg, zfin, out);
}